// Round 9
// baseline (997.783 us; speedup 1.0000x reference)
//
#include <hip/hip_runtime.h>

typedef __attribute__((ext_vector_type(4))) float f4v;
typedef __attribute__((ext_vector_type(8))) short s8v;

#define YPITCH 72   // shorts; 144 B row pitch (R3-proven)
#define NB 8        // batches per block
#define MROWS 136   // 8 x 17 rows
#define MT 9        // padded to 144 rows

static __device__ __forceinline__ short f2bf(float f) {
    unsigned u = __builtin_bit_cast(unsigned, f);
    unsigned r = (u + 0x7FFFu + ((u >> 16) & 1u)) >> 16;  // RNE
    return (short)r;
}

// W[3][256][256] (k,f,o) fp32  ->  Wt[3][256][256] (k,o,f) bf16, via LDS tile transpose
__global__ void wt_transpose_kernel(const float* __restrict__ W, short* __restrict__ Wt) {
    __shared__ short t[64][65];
    int k  = blockIdx.x >> 4;
    int r  = blockIdx.x & 15;
    int f0 = (r >> 2) << 6;
    int o0 = (r & 3) << 6;
    const float* Wk  = W  + k * 65536;
    short*       Wtk = Wt + k * 65536;
    #pragma unroll
    for (int e = 0; e < 16; e++) {
        int idx = e * 256 + threadIdx.x;
        int f = idx >> 6, o = idx & 63;
        t[f][o] = f2bf(Wk[(f0 + f) * 256 + o0 + o]);
    }
    __syncthreads();
    #pragma unroll
    for (int e = 0; e < 16; e++) {
        int idx = e * 256 + threadIdx.x;
        int o = idx >> 6, f = idx & 63;
        Wtk[(o0 + o) * 256 + f0 + f] = t[f][o];
    }
}

// One adjacency-row dot product; i and K compile-time constants after unroll. (R3-proven)
template<int K>
static __device__ __forceinline__ float row_sum(const float* __restrict__ adj,
                                                const float xq[17], int i) {
    float a;
    if (K == 0) {
        a = adj[i * 17 + i] * xq[i];
    } else if (K == 1) {
        a = 0.f;
        #pragma unroll
        for (int j = i + 1; j < 17; j++) a += adj[i * 17 + j] * xq[j];
    } else {
        a = 0.f;
        #pragma unroll
        for (int j = 0; j < i; j++) a += adj[i * 17 + j] * xq[j];
    }
    return a;
}

template<int K>
static __device__ __forceinline__ void agg_store(const float* __restrict__ adj,
                                                 const float xq[17], short* yb) {
    #pragma unroll
    for (int t = 0; t < 8; t++) {
        float a0 = row_sum<K>(adj, xq, 2 * t);
        float a1 = row_sum<K>(adj, xq, 2 * t + 1);
        unsigned r;
        asm("v_cvt_pk_bf16_f32 %0, %1, %2" : "=v"(r) : "v"(a0), "v"(a1));
        yb[(2 * t) * YPITCH]     = (short)(r & 0xffffu);
        yb[(2 * t + 1) * YPITCH] = (short)(r >> 16);
    }
    float a = row_sum<K>(adj, xq, 16);
    unsigned r;
    asm("v_cvt_pk_bf16_f32 %0, %1, %2" : "=v"(r) : "v"(a), "v"(a));
    yb[16 * YPITCH] = (short)(r & 0xffffu);
}

// One barrier region: [ wf global loads (k=KM) | agg(next step, AGGK) -> Ys[buf^1]
//                       | MFMA2(KM) <- Ys[buf] ]  then lgkm-only barrier.
// agg (VALU + ds_write) and MFMA2 (ds_read + MFMA) are independent streams in one
// basic block -> compiler co-schedules across pipes. Dbuf WAR protected by barrier.
#define REGION(FC0, KM, DOAGG, AGGK, XARR, DOBAR)                              \
    do {                                                                       \
        const short* Wtk = Wt + (KM) * 65536;                                  \
        s8v wf[2][2];                                                          \
        _Pragma("unroll")                                                      \
        for (int ks = 0; ks < 2; ks++)                                         \
            _Pragma("unroll")                                                  \
            for (int nt = 0; nt < 2; nt++)                                     \
                wf[ks][nt] = *(const s8v*)(Wtk + (wave*32 + nt*16 + mn)*256    \
                                           + (FC0) + ks*32 + quad*8);          \
        if (DOAGG)                                                             \
            agg_store<AGGK>(adj, XARR, &Ys[buf ^ 1][(bb*17)*YPITCH + f]);      \
        _Pragma("unroll")                                                      \
        for (int ks = 0; ks < 2; ks++) {                                       \
            const int ko = ks*32 + quad*8;                                     \
            _Pragma("unroll")                                                  \
            for (int mt = 0; mt < MT; mt++) {                                  \
                s8v af = *(const s8v*)(&Ys[buf][(mt*16 + mn)*YPITCH + ko]);    \
                acc[mt][0] = __builtin_amdgcn_mfma_f32_16x16x32_bf16(          \
                    wf[ks][0], af, acc[mt][0], 0, 0, 0);                       \
                acc[mt][1] = __builtin_amdgcn_mfma_f32_16x16x32_bf16(          \
                    wf[ks][1], af, acc[mt][1], 0, 0, 0);                       \
            }                                                                  \
        }                                                                      \
        if (DOBAR) {                                                           \
            asm volatile("s_waitcnt lgkmcnt(0)" ::: "memory");                 \
            __builtin_amdgcn_s_barrier();                                      \
            __builtin_amdgcn_sched_barrier(0);                                 \
        }                                                                      \
        buf ^= 1;                                                              \
    } while (0)

// One fc-chunk = 3 regions. PF: issue next chunk's x loads into XN at chunk start
// (R6-proven macro/named-array pattern -- no SROA hazard); consumed in region C
// (~2 regions of latency cover). Region C aggregates NEXT chunk's k=0.
#define CHUNK(FC0, XC, XN, PF, LASTC)                                          \
    do {                                                                       \
        if (PF) {                                                              \
            _Pragma("unroll")                                                  \
            for (int j = 0; j < 17; j++)                                       \
                XN[j] = xg[(bb*17 + j)*256 + (FC0) + 64 + f];                  \
        }                                                                      \
        REGION((FC0), 0, 1, 1, XC, 1);                                         \
        REGION((FC0), 1, 1, 2, XC, 1);                                         \
        REGION((FC0), 2, !(LASTC), 0, XN, !(LASTC));                           \
    } while (0)

// 8-wave block, NB=8: wave w aggregates batch w, owns N-slice [w*32, w*32+32).
// R3 structure with the k-step pipelined one ahead: each region overlaps
// agg(t+1) with MFMA2(t). Same barrier count (1/region), same dbuf.
// Pad rows 136..143 garbage lands only in unstored D columns (R3-proven).
__global__ __launch_bounds__(512, 4) void gconv_kernel(
        const float* __restrict__ x, const short* __restrict__ Wt,
        const float* __restrict__ adj, const float* __restrict__ bias,
        float* __restrict__ out) {
    __shared__ __align__(16) short Ys[2][144 * YPITCH];   // 2 x 20736 B = 41472 B

    const int tid  = threadIdx.x;
    const int wave = tid >> 6;       // 0..7
    const int lane = tid & 63;
    const int mn   = lane & 15;
    const int quad = lane >> 4;
    const int bb   = wave;           // batch for aggregation
    const int f    = lane;           // f-column within 64-wide chunk

    const float* xg = x   + (size_t)blockIdx.x * (NB * 17 * 256);
    float*       og = out + (size_t)blockIdx.x * (NB * 17 * 256);

    f4v acc[MT][2];
    #pragma unroll
    for (int nt = 0; nt < 2; nt++) {
        f4v bv = *(const f4v*)(bias + wave * 32 + nt * 16 + quad * 4);
        #pragma unroll
        for (int mt = 0; mt < MT; mt++) acc[mt][nt] = bv;
    }

    // prime chunk 0 + prologue agg(step 0) into Ys[0]
    float xa[17], xb[17];
    #pragma unroll
    for (int j = 0; j < 17; j++) xa[j] = xg[(bb * 17 + j) * 256 + f];
    agg_store<0>(adj, xa, &Ys[0][(bb * 17) * YPITCH + f]);
    asm volatile("s_waitcnt lgkmcnt(0)" ::: "memory");
    __builtin_amdgcn_s_barrier();
    __builtin_amdgcn_sched_barrier(0);

    int buf = 0;
    CHUNK(0,   xa, xb, 1, 0);
    CHUNK(64,  xb, xa, 1, 0);
    CHUNK(128, xa, xb, 1, 0);
    CHUNK(192, xb, xa, 0, 1);

    // ---- epilogue: D row = quad*4+rg = o (contiguous) -> one float4 store per tile ----
    #pragma unroll
    for (int mt = 0; mt < MT; mt++) {
        const int r = mt * 16 + mn;
        if (r < MROWS) {
            #pragma unroll
            for (int nt = 0; nt < 2; nt++)
                *(f4v*)(og + r * 256 + wave * 32 + nt * 16 + quad * 4) = acc[mt][nt];
        }
    }
}

extern "C" void kernel_launch(void* const* d_in, const int* in_sizes, int n_in,
                              void* d_out, int out_size, void* d_ws, size_t ws_size,
                              hipStream_t stream) {
    const float* x    = (const float*)d_in[0];
    const float* W    = (const float*)d_in[1];
    const float* adj  = (const float*)d_in[2];
    const float* bias = (const float*)d_in[3];
    float* out = (float*)d_out;
    short* Wt  = (short*)d_ws;  // 3*256*256 bf16 = 393216 B

    hipLaunchKernelGGL(wt_transpose_kernel, dim3(48), dim3(256), 0, stream, W, Wt);
    hipLaunchKernelGGL(gconv_kernel, dim3(16384 / NB), dim3(512), 0, stream,
                       x, Wt, adj, bias, out);
}